// Round 17
// baseline (462.325 us; speedup 1.0000x reference)
//
#include <hip/hip_runtime.h>

typedef unsigned long long u64;
typedef unsigned int u32;
typedef unsigned short u16;
typedef float f32x4 __attribute__((ext_vector_type(4)));
typedef __bf16 bf16x8 __attribute__((ext_vector_type(8)));

#define N_TOK 32768

// ---------- helpers ----------
__device__ inline u16 f2bf(float f){
  u32 x = __float_as_uint(f);
  u32 r = x + 0x7FFFu + ((x >> 16) & 1u);
  return (u16)(r >> 16);
}

// 1-op RNE f32->bf16 via hardware pack (low half)
__device__ inline u16 f2bf_hw(float f){
  u32 pk;
  asm("v_cvt_pk_bf16_f32 %0, %1, %2" : "=v"(pk) : "v"(f), "v"(0.f));
  return (u16)pk;
}

__device__ inline f32x4 mfma16(bf16x8 a, bf16x8 b, f32x4 c){
  return __builtin_amdgcn_mfma_f32_16x16x32_bf16(a, b, c, 0, 0, 0);
}

// raw hardware exp2 / rcp (1 VALU op; ocml adds fixup we don't need at our ranges)
__device__ inline float fexp2(float x){
  float r;
  asm("v_exp_f32 %0, %1" : "=v"(r) : "v"(x));
  return r;
}
__device__ inline float frcp(float x){
  float r;
  asm("v_rcp_f32 %0, %1" : "=v"(r) : "v"(x));
  return r;
}

typedef const __attribute__((address_space(1))) unsigned int* gas_ptr;
typedef __attribute__((address_space(3))) unsigned int* las_ptr;
__device__ inline void gload_lds16(const u16* g, u16* l){
  __builtin_amdgcn_global_load_lds((gas_ptr)g, (las_ptr)l, 16, 0, 0);
}

// rolled-perm lookup: token index at sorted position j (with shifted-window roll)
__device__ inline u32 rp_idx(const u64* __restrict__ keys, int j, int shift){
  return (u32)(keys[(j + N_TOK - shift) & (N_TOK - 1)] & 0xFFFFull);
}

__device__ inline float gelu_tanh(float x){
  float u = 0.7978845608028654f * (x + 0.044715f * x * x * x);
  float e = fexp2(2.8853900817779268f * u);      // e^{2u} = 2^{2u*log2(e)}
  return 0.5f * x * (2.0f - 2.0f * frcp(e + 1.0f));  // 0.5x(1+tanh(u)), inf-safe
}

__device__ inline u32 part1by2(u32 v){
  v &= 0x3FFu;
  v = (v | (v << 16)) & 0x030000FFu;
  v = (v | (v << 8))  & 0x0300F00Fu;
  v = (v | (v << 4))  & 0x030C30C3u;
  v = (v | (v << 2))  & 0x09249249u;
  return v;
}

// branchless compare-exchange: min-first if asc
__device__ inline void ce64(u64& a, u64& b, bool asc){
  u64 lo = a < b ? a : b;
  u64 hi = a < b ? b : a;
  a = asc ? lo : hi;
  b = asc ? hi : lo;
}

// bijective XCD-chunk swizzle (nwg % 8 == 0): each XCD gets a contiguous chunk
__device__ inline int xcd_swz(int bid, int nwg){
  int cpx = nwg >> 3;
  return (bid & 7) * cpx + (bid >> 3);
}

// ---------- coords min/max: LDS atomics + global u32 atomics (coords>=0) ----------
__global__ void minmax_init(u32* __restrict__ cmm){
  int t = threadIdx.x;
  if (t < 3) cmm[t] = 0xFFFFFFFFu;        // min slots
  else if (t < 6) cmm[t] = 0u;            // max slots
}

__global__ void __launch_bounds__(256) minmax_atomic(const float* __restrict__ coords,
                                                     u32* __restrict__ cmm){
  __shared__ u32 smn[3], smx[3];
  int t = threadIdx.x;
  if (t < 3){ smn[t] = 0xFFFFFFFFu; smx[t] = 0u; }
  __syncthreads();
  int i = blockIdx.x * 256 + t;           // over 98304 elements
  u32 bits = __float_as_uint(coords[i]);
  int a = i % 3;
  atomicMin(&smn[a], bits);
  atomicMax(&smx[a], bits);
  __syncthreads();
  if (t < 3){
    atomicMin(&cmm[t], smn[t]);
    atomicMax(&cmm[3 + t], smx[t]);
  }
}

// ---------- weight convert + transpose, all 4 weights in one launch ----------
// block ranges: [0,384) qkv, [384,512) proj, [512,1024) fc1, [1024,1536) fc2
__global__ void __launch_bounds__(256) wprep_all(
    const float* __restrict__ w_qkv, const float* __restrict__ w_proj,
    const float* __restrict__ w_fc1, const float* __restrict__ w_fc2,
    u16* __restrict__ d_qkv, u16* __restrict__ d_proj,
    u16* __restrict__ d_fc1, u16* __restrict__ d_fc2){
  int b = blockIdx.x;
  const float* src; u16* dst; int K, Nn;
  if (b < 384){ src = w_qkv; dst = d_qkv; K = 256; Nn = 768; }
  else if (b < 512){ b -= 384; src = w_proj; dst = d_proj; K = 256; Nn = 256; }
  else if (b < 1024){ b -= 512; src = w_fc1; dst = d_fc1; K = 256; Nn = 1024; }
  else { b -= 1024; src = w_fc2; dst = d_fc2; K = 1024; Nn = 256; }
  int ntx = Nn >> 5;
  int tpl = (K >> 5) * ntx;
  int layer = b / tpl, tb = b % tpl;
  src += (size_t)layer * K * Nn;
  dst += (size_t)layer * K * Nn;
  int tk = tb / ntx, tn = tb % ntx;
  __shared__ float tile[32][33];
  int r = threadIdx.x >> 5, c = threadIdx.x & 31;
  for (int rr = r; rr < 32; rr += 8)
    tile[rr][c] = src[(size_t)(tk*32 + rr) * Nn + tn*32 + c];
  __syncthreads();
  for (int rr = r; rr < 32; rr += 8)
    dst[(size_t)(tn*32 + rr) * K + tk*32 + c] = f2bf(tile[c][rr]);
}

// ---------- morton keys, both layers at once: keys[2][N_TOK] ----------
__global__ void __launch_bounds__(256) codes_kernel(const float* __restrict__ coords,
                                                    const float* __restrict__ cmm,
                                                    u64* __restrict__ keys){
  int p = blockIdx.x * 256 + threadIdx.x;   // 0 .. 2*N_TOK
  int layer = p >> 15, t = p & (N_TOK - 1);
  u32 code = 0;
  #pragma unroll
  for (int j = 0; j < 3; ++j){
    int ax = (j + layer) % 3;
    float c = coords[t*3 + ax];
    float mn = cmm[ax], mx = cmm[3 + ax];
    float v = (c - mn) / (mx - mn + 1e-9f) * 1023.0f;  // matches jax arithmetic
    int q = (int)v;
    q = q < 0 ? 0 : (q > 1023 ? 1023 : q);
    code |= part1by2((u32)q) << j;
  }
  keys[p] = ((u64)code << 16) | (u32)t;  // idx in low bits -> stable
}

// ---------- sort stage 0: one wave sorts 1024 keys (regs + shuffles, no LDS) ----------
__global__ void __launch_bounds__(64) sort_wave1024(u64* __restrict__ keys){
  int chunk = blockIdx.x;                 // 64 chunks over [2][N_TOK]
  int lane = threadIdx.x;
  int base = chunk * 1024 + lane * 16;
  int bl = base & (N_TOK - 1);            // segment-local index of v[0]
  u64 v[16];
  #pragma unroll
  for (int p = 0; p < 16; ++p) v[p] = keys[base + p];
  // levels k=2..16 fully in-register (asc per element)
  #pragma unroll
  for (int k2 = 2; k2 <= 16; k2 <<= 1){
    #pragma unroll
    for (int j = k2 >> 1; j > 0; j >>= 1){
      #pragma unroll
      for (int p = 0; p < 16; ++p){
        if ((p & j) == 0){
          bool asc = (((bl + p) & k2) == 0);
          ce64(v[p], v[p+j], asc);
        }
      }
    }
  }
  // levels k=32..1024: cross-lane via shfl_xor (j>=16), in-reg tail (j<=8)
  #pragma unroll
  for (int kk = 32; kk <= 1024; kk <<= 1){
    bool asc = ((bl & kk) == 0);          // uniform per thread (p bits < 4 < log2 kk)
    #pragma unroll
    for (int j = kk >> 1; j >= 16; j >>= 1){
      int m = j >> 4;
      bool kmin = asc != ((lane & m) != 0);
      #pragma unroll
      for (int p = 0; p < 16; ++p){
        u64 pv = __shfl_xor(v[p], m);
        u64 mn = v[p] < pv ? v[p] : pv;
        u64 mx = v[p] < pv ? pv : v[p];
        v[p] = kmin ? mn : mx;
      }
    }
    #pragma unroll
    for (int j = 8; j > 0; j >>= 1)
      #pragma unroll
      for (int p = 0; p < 16; ++p)
        if ((p & j) == 0) ce64(v[p], v[p+j], asc);
  }
  #pragma unroll
  for (int p = 0; p < 16; ++p) keys[base + p] = v[p];
}

// ---------- sort stage 1: strided bitonic steps j = (J<<(R-1)) .. J, radix 2^R ----------
template<int R>
__global__ void __launch_bounds__(256) sort_strided(u64* __restrict__ keys, int logJ, int k){
  const int E = 1 << R;
  int gps = N_TOK >> R;                    // groups per segment
  int tid = blockIdx.x * 256 + threadIdx.x;
  int seg = tid / gps, gamma = tid % gps;
  int high = gamma >> logJ, low = gamma & ((1 << logJ) - 1);
  int base = seg * N_TOK + (high << (logJ + R)) + low;
  u64 v[E];
  #pragma unroll
  for (int m = 0; m < E; ++m) v[m] = keys[base + (m << logJ)];
  bool asc = (((base & (N_TOK - 1)) & k) == 0);
  #pragma unroll
  for (int jj = R - 1; jj >= 0; --jj)
    #pragma unroll
    for (int m = 0; m < E; ++m)
      if ((m & (1 << jj)) == 0) ce64(v[m], v[m + (1 << jj)], asc);
  #pragma unroll
  for (int m = 0; m < E; ++m) keys[base + (m << logJ)] = v[m];
}

// ---------- sort stage 2: tail j=512..1 within sorted-direction 1024-chunks ----------
__global__ void __launch_bounds__(64) sort_tail1024(u64* __restrict__ keys, int k){
  int chunk = blockIdx.x;
  int lane = threadIdx.x;
  int base = chunk * 1024 + lane * 16;
  bool asc = ((((chunk * 1024) & (N_TOK - 1)) & k) == 0);   // uniform per chunk
  u64 v[16];
  #pragma unroll
  for (int p = 0; p < 16; ++p) v[p] = keys[base + p];
  #pragma unroll
  for (int m = 32; m >= 1; m >>= 1){      // j = 512..16
    bool kmin = asc != ((lane & m) != 0);
    #pragma unroll
    for (int p = 0; p < 16; ++p){
      u64 pv = __shfl_xor(v[p], m);
      u64 mn = v[p] < pv ? v[p] : pv;
      u64 mx = v[p] < pv ? pv : v[p];
      v[p] = kmin ? mn : mx;
    }
  }
  #pragma unroll
  for (int j = 8; j > 0; j >>= 1)
    #pragma unroll
    for (int p = 0; p < 16; ++p)
      if ((p & j) == 0) ce64(v[p], v[p+j], asc);
  #pragma unroll
  for (int p = 0; p < 16; ++p) keys[base + p] = v[p];
}

// ---------- gather + LN1 + positional projection d = c.w_pos ----------
__global__ void __launch_bounds__(256) gather_ln1_kernel(
    const float* __restrict__ xin, const float* __restrict__ coords,
    const u64* __restrict__ keys, int shift,
    const float* __restrict__ g1, const float* __restrict__ b1,
    const float* __restrict__ wpos,           // [3][8] for this layer
    float* __restrict__ dproj, u16* __restrict__ h){
  int w = threadIdx.x >> 6, lane = threadIdx.x & 63;
  int j = blockIdx.x * 4 + w;
  u32 src = rp_idx(keys, j, shift);
  float4 v = ((const float4*)xin)[(size_t)src * 64 + lane];
  float s = v.x + v.y + v.z + v.w;
  for (int m = 1; m < 64; m <<= 1) s += __shfl_xor(s, m);
  float mean = s * (1.0f / 256.0f);
  float dx = v.x - mean, dy = v.y - mean, dz = v.z - mean, dw = v.w - mean;
  float q = dx*dx + dy*dy + dz*dz + dw*dw;
  for (int m = 1; m < 64; m <<= 1) q += __shfl_xor(q, m);
  float rs = rsqrtf(q * (1.0f / 256.0f) + 1e-5f);
  int c0 = lane * 4;
  u16 h0 = f2bf(dx * rs * g1[c0+0] + b1[c0+0]);
  u16 h1 = f2bf(dy * rs * g1[c0+1] + b1[c0+1]);
  u16 h2 = f2bf(dz * rs * g1[c0+2] + b1[c0+2]);
  u16 h3 = f2bf(dw * rs * g1[c0+3] + b1[c0+3]);
  uint2 pk; pk.x = (u32)h0 | ((u32)h1 << 16); pk.y = (u32)h2 | ((u32)h3 << 16);
  *(uint2*)&h[(size_t)j * 256 + c0] = pk;
  if (lane < 8){
    float acc = 0.0f;
    #pragma unroll
    for (int c = 0; c < 3; ++c) acc += coords[(size_t)src*3 + c] * wpos[c*8 + lane];
    dproj[(size_t)j * 8 + lane] = acc;
  }
}

// ---------- LN (bf16 out) ----------
__global__ void __launch_bounds__(256) ln_bf16_kernel(const float* __restrict__ xin,
    const float* __restrict__ g, const float* __restrict__ b, u16* __restrict__ out){
  int w = threadIdx.x >> 6, lane = threadIdx.x & 63;
  int j = blockIdx.x * 4 + w;
  float4 v = ((const float4*)xin)[(size_t)j * 64 + lane];
  float s = v.x + v.y + v.z + v.w;
  for (int m = 1; m < 64; m <<= 1) s += __shfl_xor(s, m);
  float mean = s * (1.0f / 256.0f);
  float dx = v.x - mean, dy = v.y - mean, dz = v.z - mean, dw = v.w - mean;
  float q = dx*dx + dy*dy + dz*dz + dw*dw;
  for (int m = 1; m < 64; m <<= 1) q += __shfl_xor(q, m);
  float rs = rsqrtf(q * (1.0f / 256.0f) + 1e-5f);
  int c0 = lane * 4;
  u16 h0 = f2bf(dx * rs * g[c0+0] + b[c0+0]);
  u16 h1 = f2bf(dy * rs * g[c0+1] + b[c0+1]);
  u16 h2 = f2bf(dz * rs * g[c0+2] + b[c0+2]);
  u16 h3 = f2bf(dw * rs * g[c0+3] + b[c0+3]);
  uint2 pk; pk.x = (u32)h0 | ((u32)h1 << 16); pk.y = (u32)h2 | ((u32)h3 << 16);
  *(uint2*)&out[(size_t)j * 256 + c0] = pk;
}

// ---------- final LN (f32 out) ----------
__global__ void __launch_bounds__(256) ln_final_kernel(const float* __restrict__ xin,
    const float* __restrict__ g, const float* __restrict__ b, float* __restrict__ out){
  int w = threadIdx.x >> 6, lane = threadIdx.x & 63;
  int j = blockIdx.x * 4 + w;
  float4 v = ((const float4*)xin)[(size_t)j * 64 + lane];
  float s = v.x + v.y + v.z + v.w;
  for (int m = 1; m < 64; m <<= 1) s += __shfl_xor(s, m);
  float mean = s * (1.0f / 256.0f);
  float dx = v.x - mean, dy = v.y - mean, dz = v.z - mean, dw = v.w - mean;
  float q = dx*dx + dy*dy + dz*dz + dw*dw;
  for (int m = 1; m < 64; m <<= 1) q += __shfl_xor(q, m);
  float rs = rsqrtf(q * (1.0f / 256.0f) + 1e-5f);
  int c0 = lane * 4;
  float4 o;
  o.x = dx * rs * g[c0+0] + b[c0+0];
  o.y = dy * rs * g[c0+1] + b[c0+1];
  o.z = dz * rs * g[c0+2] + b[c0+2];
  o.w = dw * rs * g[c0+3] + b[c0+3];
  ((float4*)out)[(size_t)j * 64 + lane] = o;
}

// ---------- GEMM2: BMxBN tile, 1024 threads, XCD-chunk swizzle ----------
// A re-read count = Nn/BN, so BN is chosen per-GEMM to minimize A traffic
// (B is always <=2MB -> L2-resident). BM=128 duplicates A staging across the
// two thread halves (benign same-data race; keeps per-wave load counts
// uniform so counted vmcnt works). Dynamic LDS: (BM+BN)*128 bytes.
// EPI 0 (qkv): bf16 out, Q cols (<256) pre-scaled by SC2. EPI 1: gelu->bf16.
// EPI 3 (fc2): f32 out[scatter(row)] = res[row] + v (output stride 256).
template<int EPI, int BM, int BN>
__global__ void __launch_bounds__(1024) gemm2_kernel(
    const u16* __restrict__ A, const u16* __restrict__ Wt,
    const float* __restrict__ bias, int K, int Nn,
    u16* __restrict__ outb, float* __restrict__ outf,
    const float* __restrict__ res, const u64* __restrict__ keys, int shift){
  constexpr int WN = BN / 64;             // waves along N (SPANN = 64)
  constexpr int WM = 16 / WN;             // waves along M
  constexpr int MI = (BM / WM) / 16;
  constexpr int NI = 4;                   // 64/16
  constexpr int SPANM = BM / WM;
  constexpr int BPT = BN / 256;           // B chunks per thread (1 or 2)
  constexpr int NLD = 1 + BPT;            // loads per thread per K-step
  extern __shared__ __align__(16) u16 smem[];   // [2][(BM+BN)*32]
  int swz = xcd_swz(blockIdx.x, gridDim.x);
  int ntiles = Nn / BN;
  int m0 = (swz / ntiles) * BM;
  int n0 = (swz % ntiles) * BN;
  int tid = threadIdx.x;
  int lane = tid & 63, lc = lane & 15, g = lane >> 4;
  int w = tid >> 6;
  int wm = w / WN, wn = w % WN;
  f32x4 acc[MI][NI];
  #pragma unroll
  for (int mi = 0; mi < MI; ++mi)
    #pragma unroll
    for (int ni = 0; ni < NI; ++ni) acc[mi][ni] = (f32x4){0.f,0.f,0.f,0.f};
  int aC = tid & (BM*4 - 1);              // duplicated when BM*4 < 1024
  int rA = aC >> 2, sA = aC & 3;
  const u16* Ag = A + (size_t)(m0 + rA) * K + (sA ^ ((rA >> 1) & 3)) * 8;
  int aofs = (aC & ~63) * 8;
  const u16* Bg[BPT];
  int bofs[BPT];
  #pragma unroll
  for (int j = 0; j < BPT; ++j){
    int c = tid + j*1024;
    int rB = c >> 2, sB = c & 3;
    Bg[j] = Wt + (size_t)(n0 + rB) * K + (sB ^ ((rB >> 1) & 3)) * 8;
    bofs[j] = (c & ~63) * 8;
  }
  constexpr int BUF = (BM + BN) * 32;     // u16 per buffer
  int nt = K >> 5;
  auto issue = [&](int t, int b){
    int kk = t << 5;
    u16* Asb = smem + b * BUF;
    u16* Bsb = Asb + BM * 32;
    gload_lds16(Ag + kk, Asb + aofs);
    #pragma unroll
    for (int j = 0; j < BPT; ++j)
      gload_lds16(Bg[j] + kk, Bsb + bofs[j]);
  };
  issue(0, 0);
  int cur = 0;
  int fsw = (lc >> 1) & 3;                // read swizzle: (row>>1)&3 == (lc>>1)&3
  for (int t = 0; t < nt; ++t){
    if (t + 1 < nt){
      issue(t + 1, cur ^ 1);
      if constexpr (NLD == 2)
        asm volatile("s_waitcnt vmcnt(2)" ::: "memory");  // tile t landed; t+1 in flight
      else
        asm volatile("s_waitcnt vmcnt(3)" ::: "memory");
    } else {
      asm volatile("s_waitcnt vmcnt(0)" ::: "memory");
    }
    __builtin_amdgcn_s_barrier();          // publish tile t
    const u16* Asb = smem + cur * BUF;
    const u16* Bsb = Asb + BM * 32;
    bf16x8 af[MI], bfr[NI];
    #pragma unroll
    for (int mi = 0; mi < MI; ++mi)
      af[mi] = *(const bf16x8*)&Asb[(wm*SPANM + mi*16 + lc)*32 + (g ^ fsw)*8];
    #pragma unroll
    for (int ni = 0; ni < NI; ++ni)
      bfr[ni] = *(const bf16x8*)&Bsb[(wn*64 + ni*16 + lc)*32 + (g ^ fsw)*8];
    #pragma unroll
    for (int mi = 0; mi < MI; ++mi)
      #pragma unroll
      for (int ni = 0; ni < NI; ++ni)
        acc[mi][ni] = mfma16(af[mi], bfr[ni], acc[mi][ni]);
    asm volatile("" ::: "memory");         // pin ds_reads above the barrier
    __builtin_amdgcn_s_barrier();          // buf[cur] reusable
    cur ^= 1;
  }
  if constexpr (EPI == 0 || EPI == 1){
    float bv[NI];
    #pragma unroll
    for (int ni = 0; ni < NI; ++ni) bv[ni] = bias[n0 + wn*64 + ni*16 + lc];
    #pragma unroll
    for (int mi = 0; mi < MI; ++mi){
      #pragma unroll
      for (int r = 0; r < 4; ++r){
        int row = m0 + wm*SPANM + mi*16 + g*4 + r;
        u16* rowp = outb + (size_t)row * Nn + n0 + wn*64 + lc;
        #pragma unroll
        for (int ni = 0; ni < NI; ++ni){   // consecutive 32B segments of one row
          int col = n0 + wn*64 + ni*16 + lc;
          float v = acc[mi][ni][r] + bv[ni];
          if constexpr (EPI == 0){
            if (col < 256) v *= 0.25500526f;   // Q pre-scale: (1/sqrt(32))*log2(e)
          } else {
            v = gelu_tanh(v);
          }
          rowp[ni*16] = f2bf_hw(v);
        }
      }
    }
  } else {
    #pragma unroll
    for (int ni = 0; ni < NI; ++ni){
      int col = n0 + wn*64 + ni*16 + lc;
      float bv = bias[col];
      #pragma unroll
      for (int mi = 0; mi < MI; ++mi){
        #pragma unroll
        for (int r = 0; r < 4; ++r){
          int row = m0 + wm*SPANM + mi*16 + g*4 + r;
          float v = acc[mi][ni][r] + bv;
          u32 dst = rp_idx(keys, row, shift);
          outf[(size_t)dst * 256 + col] = res[(size_t)row * 256 + col] + v;
        }
      }
    }
  }
}

// ---------- GEMM (128x128, 256 thr): proj (EPI2: res[gather(row)] + v), XCD swizzle ----------
template<int EPI>
__global__ void __launch_bounds__(256) gemm_kernel(
    const u16* __restrict__ A, const u16* __restrict__ Wt,
    const float* __restrict__ bias, int K, int Nn,
    u16* __restrict__ outb, float* __restrict__ outf,
    const float* __restrict__ res, const u64* __restrict__ keys, int shift){
  __shared__ __align__(16) u16 As[2][128 * 32];
  __shared__ __align__(16) u16 Bs[2][128 * 32];
  int swz = xcd_swz(blockIdx.x, gridDim.x);
  int ntiles = Nn / 128;
  int m0 = (swz / ntiles) * 128;
  int n0 = (swz % ntiles) * 128;
  int tid = threadIdx.x;
  int lane = tid & 63, lc = lane & 15, g = lane >> 4;
  int w = tid >> 6, wm = w >> 1, wn = w & 1;
  f32x4 acc[4][4];
  #pragma unroll
  for (int mi = 0; mi < 4; ++mi)
    #pragma unroll
    for (int ni = 0; ni < 4; ++ni) acc[mi][ni] = (f32x4){0.f,0.f,0.f,0.f};
  int r1 = tid >> 2, s1 = tid & 3;
  int r2 = r1 + 64;
  int sw = s1 ^ ((r1 >> 1) & 3);
  const u16* Ag1 = A  + (size_t)(m0 + r1) * K + sw*8;
  const u16* Ag2 = A  + (size_t)(m0 + r2) * K + sw*8;
  const u16* Bg1 = Wt + (size_t)(n0 + r1) * K + sw*8;
  const u16* Bg2 = Wt + (size_t)(n0 + r2) * K + sw*8;
  int wofs = (tid & ~63) * 8;
  int nt = K >> 5;
  gload_lds16(Ag1, As[0] + wofs);
  gload_lds16(Ag2, As[0] + wofs + 2048);
  gload_lds16(Bg1, Bs[0] + wofs);
  gload_lds16(Bg2, Bs[0] + wofs + 2048);
  int cur = 0;
  int fsw = (lc >> 1) & 3;
  for (int t = 0; t < nt; ++t){
    if (t + 1 < nt){
      int kk = (t + 1) << 5;
      gload_lds16(Ag1 + kk, As[cur^1] + wofs);
      gload_lds16(Ag2 + kk, As[cur^1] + wofs + 2048);
      gload_lds16(Bg1 + kk, Bs[cur^1] + wofs);
      gload_lds16(Bg2 + kk, Bs[cur^1] + wofs + 2048);
      asm volatile("s_waitcnt vmcnt(4)" ::: "memory");
    } else {
      asm volatile("s_waitcnt vmcnt(0)" ::: "memory");
    }
    __builtin_amdgcn_s_barrier();
    bf16x8 af[4], bfr[4];
    #pragma unroll
    for (int mi = 0; mi < 4; ++mi)
      af[mi] = *(const bf16x8*)&As[cur][(wm*64 + mi*16 + lc)*32 + (g ^ fsw)*8];
    #pragma unroll
    for (int ni = 0; ni < 4; ++ni)
      bfr[ni] = *(const bf16x8*)&Bs[cur][(wn*64 + ni*16 + lc)*32 + (g ^ fsw)*8];
    #pragma unroll
    for (int mi = 0; mi < 4; ++mi)
      #pragma unroll
      for (int ni = 0; ni < 4; ++ni)
        acc[mi][ni] = mfma16(af[mi], bfr[ni], acc[mi][ni]);
    asm volatile("" ::: "memory");
    __builtin_amdgcn_s_barrier();
    cur ^= 1;
  }
  #pragma unroll
  for (int ni = 0; ni < 4; ++ni){
    int col = n0 + wn*64 + ni*16 + lc;
    float bv = bias[col];
    #pragma unroll
    for (int mi = 0; mi < 4; ++mi){
      #pragma unroll
      for (int r = 0; r < 4; ++r){
        int row = m0 + wm*64 + mi*16 + g*4 + r;
        float v = acc[mi][ni][r] + bv;
        if constexpr (EPI == 2){
          u32 src = rp_idx(keys, row, shift);
          outf[(size_t)row * 256 + col] = res[(size_t)src * 256 + col] + v;
        } else {
          outb[(size_t)row * Nn + col] = f2bf_hw(v);
        }
      }
    }
  }
}

// ---------- attention: swapped-QK, 2 q-tiles per K/V pass ----------
#define VSTR 516
#define ATTN_LDS (512*32*2 + 32*VSTR*2 + 512*2)
__global__ void __launch_bounds__(512) attn_kernel(
    const u16* __restrict__ qkvb, const float* __restrict__ dproj,
    u16* __restrict__ o){
  extern __shared__ char smemc[];
  u16* Kl = (u16*)smemc;                             // [512][32] swizzled chunks
  u16* Vt = (u16*)(smemc + 512*32*2);                // [32 d][VSTR] phys-slot order, w-scaled
  u16* wl = (u16*)(smemc + 512*32*2 + 32*VSTR*2);    // [512] w bf16, phys-slot order
  int h = blockIdx.x & 7;
  int base = (blockIdx.x >> 3) * 512;
  int tid = threadIdx.x, w = tid >> 6, lane = tid & 63, lc = lane & 15, g = lane >> 4;
  const float L2E = 1.4426950408889634f;
  for (int i = tid; i < 2048; i += 512){
    int j = i >> 2, s = i & 3;
    int swc = s ^ ((j >> 1) & 3);
    *(uint4*)&Kl[j*32 + s*8] =
      *(const uint4*)&qkvb[(size_t)(base + j)*768 + 256 + h*32 + swc*8];
  }
  for (int i = tid; i < 1024; i += 512){
    int p = i >> 2, d0 = (i & 3) * 8;
    int j0 = 2*p, j1 = j0 + 1;
    float wv0 = fexp2(-L2E * dproj[(size_t)(base + j0)*8 + h]);
    float wv1 = fexp2(-L2E * dproj[(size_t)(base + j1)*8 + h]);
    uint4 r0 = *(const uint4*)&qkvb[(size_t)(base + j0)*768 + 512 + h*32 + d0];
    uint4 r1 = *(const uint4*)&qkvb[(size_t)(base + j1)*768 + 512 + h*32 + d0];
    const u16* p0 = (const u16*)&r0; const u16* p1 = (const u16*)&r1;
    int j5 = j0 & 31, b = j5 >> 4, m = j5 & 15;
    int slot = (j0 & ~31) + 8*(m >> 2) + 4*b + (m & 3);   // even; slot(j1)=slot+1
    #pragma unroll
    for (int e = 0; e < 8; ++e){
      float f0 = __uint_as_float(((u32)p0[e]) << 16) * wv0;
      float f1 = __uint_as_float(((u32)p1[e]) << 16) * wv1;
      u32 pk;
      asm("v_cvt_pk_bf16_f32 %0, %1, %2" : "=v"(pk) : "v"(f0), "v"(f1));
      *(u32*)&Vt[(d0 + e)*VSTR + slot] = pk;
    }
    if (d0 == 0){
      u32 pkw;
      asm("v_cvt_pk_bf16_f32 %0, %1, %2" : "=v"(pkw) : "v"(wv0), "v"(wv1));
      *(u32*)&wl[slot] = pkw;
    }
  }
  __syncthreads();
  const f32x4 zf = {0.f,0.f,0.f,0.f};
  const u16* Qg = qkvb + (size_t)base*768 + h*32;
  int fswk = (lc >> 1) & 3;
  for (int t = 0; t < 2; ++t){
    int q0 = w*64 + t*32;
    bf16x8 qfa = *(const bf16x8*)&Qg[(size_t)(q0 + lc)*768 + g*8];
    bf16x8 qfb = *(const bf16x8*)&Qg[(size_t)(q0 + 16 + lc)*768 + g*8];
    f32x4 oa0 = zf, oa1 = zf, la = zf;
    f32x4 ob0 = zf, ob1 = zf, lb = zf;
    #pragma unroll 4
    for (int grp = 0; grp < 16; ++grp){
      int kb = grp * 32;
      bf16x8 kf0 = *(const bf16x8*)&Kl[(kb + lc)*32 + (g ^ fswk)*8];
      bf16x8 kf1 = *(const bf16x8*)&Kl[(kb + 16 + lc)*32 + (g ^ fswk)*8];
      f32x4 sa0 = mfma16(kf0, qfa, zf);
      f32x4 sa1 = mfma16(kf1, qfa, zf);
      f32x4 sb0 = mfma16(kf0, qfb, zf);
      f32x4 sb1 = mfma16(kf1, qfb, zf);
      #pragma unroll
      for (int r = 0; r < 4; ++r){
        sa0[r] = fexp2(sa0[r]); sa1[r] = fexp2(sa1[r]);
        sb0[r] = fexp2(sb0[r]); sb1[r] = fexp2(sb1[r]);
      }
      u32 ka0, ka1, ka2, ka3, kb0, kb1, kb2, kb3;
      asm("v_cvt_pk_bf16_f32 %0, %1, %2" : "=v"(ka0) : "v"(sa0[0]), "v"(sa0[1]));
      asm("v_cvt_pk_bf16_f32 %0, %1, %2" : "=v"(ka1) : "v"(sa0[2]), "v"(sa0[3]));
      asm("v_cvt_pk_bf16_f32 %0, %1, %2" : "=v"(ka2) : "v"(sa1[0]), "v"(sa1[1]));
      asm("v_cvt_pk_bf16_f32 %0, %1, %2" : "=v"(ka3) : "v"(sa1[2]), "v"(sa1[3]));
      asm("v_cvt_pk_bf16_f32 %0, %1, %2" : "=v"(kb0) : "v"(sb0[0]), "v"(sb0[1]));
      asm("v_cvt_pk_bf16_f32 %0, %1, %2" : "=v"(kb1) : "v"(sb0[2]), "v"(sb0[3]));
      asm("v_cvt_pk_bf16_f32 %0, %1, %2" : "=v"(kb2) : "v"(sb1[0]), "v"(sb1[1]));
      asm("v_cvt_pk_bf16_f32 %0, %1, %2" : "=v"(kb3) : "v"(sb1[2]), "v"(sb1[3]));
      bf16x8 pfa, pfb;
      ((u32*)&pfa)[0] = ka0; ((u32*)&pfa)[1] = ka1;
      ((u32*)&pfa)[2] = ka2; ((u32*)&pfa)[3] = ka3;
      ((u32*)&pfb)[0] = kb0; ((u32*)&pfb)[1] = kb1;
      ((u32*)&pfb)[2] = kb2; ((u32*)&pfb)[3] = kb3;
      bf16x8 v0, v1;
      *(uint2*)&v0       = *(const uint2*)&Vt[lc*VSTR + kb + g*8];
      *((uint2*)&v0 + 1) = *(const uint2*)&Vt[lc*VSTR + kb + g*8 + 4];
      *(uint2*)&v1       = *(const uint2*)&Vt[(16+lc)*VSTR + kb + g*8];
      *((uint2*)&v1 + 1) = *(const uint2*)&Vt[(16+lc)*VSTR + kb + g*8 + 4];
      bf16x8 wf = *(const bf16x8*)&wl[kb + g*8];
      __builtin_amdgcn_s_setprio(1);
      oa0 = mfma16(pfa, v0, oa0);
      oa1 = mfma16(pfa, v1, oa1);
      la  = mfma16(pfa, wf, la);
      ob0 = mfma16(pfb, v0, ob0);
      ob1 = mfma16(pfb, v1, ob1);
      lb  = mfma16(pfb, wf, lb);
      __builtin_amdgcn_s_setprio(0);
    }
    #pragma unroll
    for (int r = 0; r < 4; ++r){
      float inva = frcp(la[r]);
      float invb = frcp(lb[r]);
      size_t tokA = (size_t)(base + q0 + g*4 + r);
      size_t tokB = tokA + 16;
      o[tokA*256 + h*32 + lc]      = f2bf(oa0[r] * inva);
      o[tokA*256 + h*32 + 16 + lc] = f2bf(oa1[r] * inva);
      o[tokB*256 + h*32 + lc]      = f2bf(ob0[r] * invb);
      o[tokB*256 + h*32 + 16 + lc] = f2bf(ob1[r] * invb);
    }
  }
}

// ---------- host ----------
extern "C" void kernel_launch(void* const* d_in, const int* in_sizes, int n_in,
                              void* d_out, int out_size, void* d_ws, size_t ws_size,
                              hipStream_t stream){
  const float* x      = (const float*)d_in[0];
  const float* coords = (const float*)d_in[1];
  const float* ln1_g  = (const float*)d_in[2];
  const float* ln1_b  = (const float*)d_in[3];
  const float* w_qkv  = (const float*)d_in[4];
  const float* b_qkv  = (const float*)d_in[5];
  const float* w_proj = (const float*)d_in[6];
  const float* b_proj = (const float*)d_in[7];
  const float* w_pos  = (const float*)d_in[8];
  // d_in[9] = b_pos: cancels in softmax (row-constant), unused
  const float* ln2_g  = (const float*)d_in[10];
  const float* ln2_b  = (const float*)d_in[11];
  const float* w_fc1  = (const float*)d_in[12];
  const float* b_fc1  = (const float*)d_in[13];
  const float* w_fc2  = (const float*)d_in[14];
  const float* b_fc2  = (const float*)d_in[15];
  const float* norm_g = (const float*)d_in[16];
  const float* norm_b = (const float*)d_in[17];
  float* outp = (float*)d_out;

  // allow >64KB dynamic LDS (idempotent; not stream ops)
  hipFuncSetAttribute((const void*)attn_kernel,
                      hipFuncAttributeMaxDynamicSharedMemorySize, ATTN_LDS);
  hipFuncSetAttribute((const void*)gemm2_kernel<0,256,256>,
                      hipFuncAttributeMaxDynamicSharedMemorySize, (256+256)*128);
  hipFuncSetAttribute((const void*)gemm2_kernel<1,128,512>,
                      hipFuncAttributeMaxDynamicSharedMemorySize, (128+512)*128);
  hipFuncSetAttribute((const void*)gemm2_kernel<3,128,256>,
                      hipFuncAttributeMaxDynamicSharedMemorySize, (128+256)*128);

  char* ws = (char*)d_ws;
  size_t off = 0;
  auto alloc = [&](size_t bytes) -> void* {
    void* p = ws + off;
    off += (bytes + 255) & ~(size_t)255;
    return p;
  };
  u64*   keys   = (u64*)  alloc((size_t)2 * N_TOK * 8);     // both layers
  float* cmm    = (float*)alloc(256);
  float* dproj  = (float*)alloc((size_t)N_TOK * 8 * 4);
  u16*   h      = (u16*)  alloc((size_t)N_TOK * 256 * 2);   // also reused as h2
  u16*   qkvb   = (u16*)  alloc((size_t)N_TOK * 768 * 2);   // also reused as layer-2 output (f32)
  float* x2     = (float*)alloc((size_t)N_TOK * 256 * 4);
  u16*   t      = (u16*)  alloc((size_t)N_TOK * 1024 * 2);  // front 1/4 also reused as attn out o
  float* xA     = (float*)alloc((size_t)N_TOK * 256 * 4);
  u16*   wtqkv  = (u16*)  alloc((size_t)2 * 256 * 768 * 2);
  u16*   wtproj = (u16*)  alloc((size_t)2 * 256 * 256 * 2);
  u16*   wtfc1  = (u16*)  alloc((size_t)2 * 256 * 1024 * 2);
  u16*   wtfc2  = (u16*)  alloc((size_t)2 * 1024 * 256 * 2);
  u16*   o      = t;            // alias: o dead before fc1 writes t
  float* xB     = (float*)qkvb; // alias: layer-2 qkv dead before fc2 writes xB
  (void)in_sizes; (void)n_in; (void)out_size; (void)ws_size;

  minmax_init<<<1, 64, 0, stream>>>((u32*)cmm);
  minmax_atomic<<<384, 256, 0, stream>>>(coords, (u32*)cmm);
  wprep_all<<<1536, 256, 0, stream>>>(w_qkv, w_proj, w_fc1, w_fc2,
                                      wtqkv, wtproj, wtfc1, wtfc2);

  // both layers' sorts, batched: wave-1024 sort, then strided+tail per bitonic level
  codes_kernel<<<256, 256, 0, stream>>>(coords, cmm, keys);
  sort_wave1024<<<64, 64, 0, stream>>>(keys);
  sort_strided<1><<<128, 256, 0, stream>>>(keys, 10, 2048);
  sort_tail1024<<<64, 64, 0, stream>>>(keys, 2048);
  sort_strided<2><<<64, 256, 0, stream>>>(keys, 10, 4096);
  sort_tail1024<<<64, 64, 0, stream>>>(keys, 4096);
  sort_strided<3><<<32, 256, 0, stream>>>(keys, 10, 8192);
  sort_tail1024<<<64, 64, 0, stream>>>(keys, 8192);
  sort_strided<3><<<32, 256, 0, stream>>>(keys, 11, 16384);
  sort_strided<1><<<128, 256, 0, stream>>>(keys, 10, 16384);
  sort_tail1024<<<64, 64, 0, stream>>>(keys, 16384);
  sort_strided<3><<<32, 256, 0, stream>>>(keys, 12, 32768);
  sort_strided<2><<<64, 256, 0, stream>>>(keys, 10, 32768);
  sort_tail1024<<<64, 64, 0, stream>>>(keys, 32768);

  for (int layer = 0; layer < 2; ++layer){
    int shift = (layer & 1) ? 256 : 0;
    const float* xin = (layer == 0) ? x : xA;
    float* xout = (layer == 0) ? xA : xB;
    u64* keyL = keys + (size_t)layer * N_TOK;

    gather_ln1_kernel<<<8192, 256, 0, stream>>>(xin, coords, keyL, shift,
        ln1_g + layer*256, ln1_b + layer*256, w_pos + layer*24, dproj, h);
    gemm2_kernel<0,256,256><<<384, 1024, (256+256)*128, stream>>>(
        h, wtqkv + (size_t)layer*768*256,
        b_qkv + layer*768, 256, 768, qkvb, nullptr, nullptr, nullptr, 0);
    attn_kernel<<<512, 512, ATTN_LDS, stream>>>(qkvb, dproj, o);
    gemm_kernel<2><<<512, 256, 0, stream>>>(o, wtproj + (size_t)layer*256*256,
        b_proj + layer*256, 256, 256, nullptr, x2, xin, keyL, shift);
    ln_bf16_kernel<<<8192, 256, 0, stream>>>(x2, ln2_g + layer*256, ln2_b + layer*256, h);
    gemm2_kernel<1,128,512><<<512, 1024, (128+512)*128, stream>>>(
        h, wtfc1 + (size_t)layer*1024*256,
        b_fc1 + layer*1024, 256, 1024, t, nullptr, nullptr, nullptr, 0);
    gemm2_kernel<3,128,256><<<256, 1024, (128+256)*128, stream>>>(
        t, wtfc2 + (size_t)layer*256*1024,
        b_fc2 + layer*256, 1024, 256, nullptr, xout, x2, keyL, shift);
  }
  ln_final_kernel<<<8192, 256, 0, stream>>>(xB, norm_g, norm_b, outp);
}

// Round 18
// 460.289 us; speedup vs baseline: 1.0044x; 1.0044x over previous
//
#include <hip/hip_runtime.h>

typedef unsigned long long u64;
typedef unsigned int u32;
typedef unsigned short u16;
typedef float f32x4 __attribute__((ext_vector_type(4)));
typedef __bf16 bf16x8 __attribute__((ext_vector_type(8)));

#define N_TOK 32768

// ---------- helpers ----------
__device__ inline u16 f2bf(float f){
  u32 x = __float_as_uint(f);
  u32 r = x + 0x7FFFu + ((x >> 16) & 1u);
  return (u16)(r >> 16);
}

// 1-op RNE f32->bf16 via hardware pack (low half)
__device__ inline u16 f2bf_hw(float f){
  u32 pk;
  asm("v_cvt_pk_bf16_f32 %0, %1, %2" : "=v"(pk) : "v"(f), "v"(0.f));
  return (u16)pk;
}

__device__ inline f32x4 mfma16(bf16x8 a, bf16x8 b, f32x4 c){
  return __builtin_amdgcn_mfma_f32_16x16x32_bf16(a, b, c, 0, 0, 0);
}

// raw hardware exp2 / rcp (1 VALU op; ocml adds fixup we don't need at our ranges)
__device__ inline float fexp2(float x){
  float r;
  asm("v_exp_f32 %0, %1" : "=v"(r) : "v"(x));
  return r;
}
__device__ inline float frcp(float x){
  float r;
  asm("v_rcp_f32 %0, %1" : "=v"(r) : "v"(x));
  return r;
}

typedef const __attribute__((address_space(1))) unsigned int* gas_ptr;
typedef __attribute__((address_space(3))) unsigned int* las_ptr;
__device__ inline void gload_lds16(const u16* g, u16* l){
  __builtin_amdgcn_global_load_lds((gas_ptr)g, (las_ptr)l, 16, 0, 0);
}

// rolled-perm lookup: token index at sorted position j (with shifted-window roll)
__device__ inline u32 rp_idx(const u64* __restrict__ keys, int j, int shift){
  return (u32)(keys[(j + N_TOK - shift) & (N_TOK - 1)] & 0xFFFFull);
}

__device__ inline float gelu_tanh(float x){
  float u = 0.7978845608028654f * (x + 0.044715f * x * x * x);
  float e = fexp2(2.8853900817779268f * u);      // e^{2u} = 2^{2u*log2(e)}
  return 0.5f * x * (2.0f - 2.0f * frcp(e + 1.0f));  // 0.5x(1+tanh(u)), inf-safe
}

__device__ inline u32 part1by2(u32 v){
  v &= 0x3FFu;
  v = (v | (v << 16)) & 0x030000FFu;
  v = (v | (v << 8))  & 0x0300F00Fu;
  v = (v | (v << 4))  & 0x030C30C3u;
  v = (v | (v << 2))  & 0x09249249u;
  return v;
}

// branchless compare-exchange: min-first if asc
__device__ inline void ce64(u64& a, u64& b, bool asc){
  u64 lo = a < b ? a : b;
  u64 hi = a < b ? b : a;
  a = asc ? lo : hi;
  b = asc ? hi : lo;
}

// bijective XCD-chunk swizzle (nwg % 8 == 0): each XCD gets a contiguous chunk
__device__ inline int xcd_swz(int bid, int nwg){
  int cpx = nwg >> 3;
  return (bid & 7) * cpx + (bid >> 3);
}

// ---------- coords min/max: LDS atomics + global u32 atomics (coords>=0) ----------
__global__ void minmax_init(u32* __restrict__ cmm){
  int t = threadIdx.x;
  if (t < 3) cmm[t] = 0xFFFFFFFFu;        // min slots
  else if (t < 6) cmm[t] = 0u;            // max slots
}

__global__ void __launch_bounds__(256) minmax_atomic(const float* __restrict__ coords,
                                                     u32* __restrict__ cmm){
  __shared__ u32 smn[3], smx[3];
  int t = threadIdx.x;
  if (t < 3){ smn[t] = 0xFFFFFFFFu; smx[t] = 0u; }
  __syncthreads();
  int i = blockIdx.x * 256 + t;           // over 98304 elements
  u32 bits = __float_as_uint(coords[i]);
  int a = i % 3;
  atomicMin(&smn[a], bits);
  atomicMax(&smx[a], bits);
  __syncthreads();
  if (t < 3){
    atomicMin(&cmm[t], smn[t]);
    atomicMax(&cmm[3 + t], smx[t]);
  }
}

// ---------- weight convert + transpose, all 4 weights in one launch ----------
// block ranges: [0,384) qkv, [384,512) proj, [512,1024) fc1, [1024,1536) fc2
__global__ void __launch_bounds__(256) wprep_all(
    const float* __restrict__ w_qkv, const float* __restrict__ w_proj,
    const float* __restrict__ w_fc1, const float* __restrict__ w_fc2,
    u16* __restrict__ d_qkv, u16* __restrict__ d_proj,
    u16* __restrict__ d_fc1, u16* __restrict__ d_fc2){
  int b = blockIdx.x;
  const float* src; u16* dst; int K, Nn;
  if (b < 384){ src = w_qkv; dst = d_qkv; K = 256; Nn = 768; }
  else if (b < 512){ b -= 384; src = w_proj; dst = d_proj; K = 256; Nn = 256; }
  else if (b < 1024){ b -= 512; src = w_fc1; dst = d_fc1; K = 256; Nn = 1024; }
  else { b -= 1024; src = w_fc2; dst = d_fc2; K = 1024; Nn = 256; }
  int ntx = Nn >> 5;
  int tpl = (K >> 5) * ntx;
  int layer = b / tpl, tb = b % tpl;
  src += (size_t)layer * K * Nn;
  dst += (size_t)layer * K * Nn;
  int tk = tb / ntx, tn = tb % ntx;
  __shared__ float tile[32][33];
  int r = threadIdx.x >> 5, c = threadIdx.x & 31;
  for (int rr = r; rr < 32; rr += 8)
    tile[rr][c] = src[(size_t)(tk*32 + rr) * Nn + tn*32 + c];
  __syncthreads();
  for (int rr = r; rr < 32; rr += 8)
    dst[(size_t)(tn*32 + rr) * K + tk*32 + c] = f2bf(tile[c][rr]);
}

// ---------- morton keys, both layers at once: keys[2][N_TOK] ----------
__global__ void __launch_bounds__(256) codes_kernel(const float* __restrict__ coords,
                                                    const float* __restrict__ cmm,
                                                    u64* __restrict__ keys){
  int p = blockIdx.x * 256 + threadIdx.x;   // 0 .. 2*N_TOK
  int layer = p >> 15, t = p & (N_TOK - 1);
  u32 code = 0;
  #pragma unroll
  for (int j = 0; j < 3; ++j){
    int ax = (j + layer) % 3;
    float c = coords[t*3 + ax];
    float mn = cmm[ax], mx = cmm[3 + ax];
    float v = (c - mn) / (mx - mn + 1e-9f) * 1023.0f;  // matches jax arithmetic
    int q = (int)v;
    q = q < 0 ? 0 : (q > 1023 ? 1023 : q);
    code |= part1by2((u32)q) << j;
  }
  keys[p] = ((u64)code << 16) | (u32)t;  // idx in low bits -> stable
}

// ---------- sort stage 0: one wave sorts 1024 keys (regs + shuffles, no LDS) ----------
__global__ void __launch_bounds__(64) sort_wave1024(u64* __restrict__ keys){
  int chunk = blockIdx.x;                 // 64 chunks over [2][N_TOK]
  int lane = threadIdx.x;
  int base = chunk * 1024 + lane * 16;
  int bl = base & (N_TOK - 1);            // segment-local index of v[0]
  u64 v[16];
  #pragma unroll
  for (int p = 0; p < 16; ++p) v[p] = keys[base + p];
  // levels k=2..16 fully in-register (asc per element)
  #pragma unroll
  for (int k2 = 2; k2 <= 16; k2 <<= 1){
    #pragma unroll
    for (int j = k2 >> 1; j > 0; j >>= 1){
      #pragma unroll
      for (int p = 0; p < 16; ++p){
        if ((p & j) == 0){
          bool asc = (((bl + p) & k2) == 0);
          ce64(v[p], v[p+j], asc);
        }
      }
    }
  }
  // levels k=32..1024: cross-lane via shfl_xor (j>=16), in-reg tail (j<=8)
  #pragma unroll
  for (int kk = 32; kk <= 1024; kk <<= 1){
    bool asc = ((bl & kk) == 0);          // uniform per thread (p bits < 4 < log2 kk)
    #pragma unroll
    for (int j = kk >> 1; j >= 16; j >>= 1){
      int m = j >> 4;
      bool kmin = asc != ((lane & m) != 0);
      #pragma unroll
      for (int p = 0; p < 16; ++p){
        u64 pv = __shfl_xor(v[p], m);
        u64 mn = v[p] < pv ? v[p] : pv;
        u64 mx = v[p] < pv ? pv : v[p];
        v[p] = kmin ? mn : mx;
      }
    }
    #pragma unroll
    for (int j = 8; j > 0; j >>= 1)
      #pragma unroll
      for (int p = 0; p < 16; ++p)
        if ((p & j) == 0) ce64(v[p], v[p+j], asc);
  }
  #pragma unroll
  for (int p = 0; p < 16; ++p) keys[base + p] = v[p];
}

// ---------- sort stage 1: strided bitonic steps j = (J<<(R-1)) .. J, radix 2^R ----------
template<int R>
__global__ void __launch_bounds__(256) sort_strided(u64* __restrict__ keys, int logJ, int k){
  const int E = 1 << R;
  int gps = N_TOK >> R;                    // groups per segment
  int tid = blockIdx.x * 256 + threadIdx.x;
  int seg = tid / gps, gamma = tid % gps;
  int high = gamma >> logJ, low = gamma & ((1 << logJ) - 1);
  int base = seg * N_TOK + (high << (logJ + R)) + low;
  u64 v[E];
  #pragma unroll
  for (int m = 0; m < E; ++m) v[m] = keys[base + (m << logJ)];
  bool asc = (((base & (N_TOK - 1)) & k) == 0);
  #pragma unroll
  for (int jj = R - 1; jj >= 0; --jj)
    #pragma unroll
    for (int m = 0; m < E; ++m)
      if ((m & (1 << jj)) == 0) ce64(v[m], v[m + (1 << jj)], asc);
  #pragma unroll
  for (int m = 0; m < E; ++m) keys[base + (m << logJ)] = v[m];
}

// ---------- sort stage 2: tail j=512..1 within sorted-direction 1024-chunks ----------
__global__ void __launch_bounds__(64) sort_tail1024(u64* __restrict__ keys, int k){
  int chunk = blockIdx.x;
  int lane = threadIdx.x;
  int base = chunk * 1024 + lane * 16;
  bool asc = ((((chunk * 1024) & (N_TOK - 1)) & k) == 0);   // uniform per chunk
  u64 v[16];
  #pragma unroll
  for (int p = 0; p < 16; ++p) v[p] = keys[base + p];
  #pragma unroll
  for (int m = 32; m >= 1; m >>= 1){      // j = 512..16
    bool kmin = asc != ((lane & m) != 0);
    #pragma unroll
    for (int p = 0; p < 16; ++p){
      u64 pv = __shfl_xor(v[p], m);
      u64 mn = v[p] < pv ? v[p] : pv;
      u64 mx = v[p] < pv ? pv : v[p];
      v[p] = kmin ? mn : mx;
    }
  }
  #pragma unroll
  for (int j = 8; j > 0; j >>= 1)
    #pragma unroll
    for (int p = 0; p < 16; ++p)
      if ((p & j) == 0) ce64(v[p], v[p+j], asc);
  #pragma unroll
  for (int p = 0; p < 16; ++p) keys[base + p] = v[p];
}

// ---------- gather + LN1 + positional projection d = c.w_pos ----------
__global__ void __launch_bounds__(256) gather_ln1_kernel(
    const float* __restrict__ xin, const float* __restrict__ coords,
    const u64* __restrict__ keys, int shift,
    const float* __restrict__ g1, const float* __restrict__ b1,
    const float* __restrict__ wpos,           // [3][8] for this layer
    float* __restrict__ dproj, u16* __restrict__ h){
  int w = threadIdx.x >> 6, lane = threadIdx.x & 63;
  int j = blockIdx.x * 4 + w;
  u32 src = rp_idx(keys, j, shift);
  float4 v = ((const float4*)xin)[(size_t)src * 64 + lane];
  float s = v.x + v.y + v.z + v.w;
  for (int m = 1; m < 64; m <<= 1) s += __shfl_xor(s, m);
  float mean = s * (1.0f / 256.0f);
  float dx = v.x - mean, dy = v.y - mean, dz = v.z - mean, dw = v.w - mean;
  float q = dx*dx + dy*dy + dz*dz + dw*dw;
  for (int m = 1; m < 64; m <<= 1) q += __shfl_xor(q, m);
  float rs = rsqrtf(q * (1.0f / 256.0f) + 1e-5f);
  int c0 = lane * 4;
  u16 h0 = f2bf(dx * rs * g1[c0+0] + b1[c0+0]);
  u16 h1 = f2bf(dy * rs * g1[c0+1] + b1[c0+1]);
  u16 h2 = f2bf(dz * rs * g1[c0+2] + b1[c0+2]);
  u16 h3 = f2bf(dw * rs * g1[c0+3] + b1[c0+3]);
  uint2 pk; pk.x = (u32)h0 | ((u32)h1 << 16); pk.y = (u32)h2 | ((u32)h3 << 16);
  *(uint2*)&h[(size_t)j * 256 + c0] = pk;
  if (lane < 8){
    float acc = 0.0f;
    #pragma unroll
    for (int c = 0; c < 3; ++c) acc += coords[(size_t)src*3 + c] * wpos[c*8 + lane];
    dproj[(size_t)j * 8 + lane] = acc;
  }
}

// ---------- LN (bf16 out) ----------
__global__ void __launch_bounds__(256) ln_bf16_kernel(const float* __restrict__ xin,
    const float* __restrict__ g, const float* __restrict__ b, u16* __restrict__ out){
  int w = threadIdx.x >> 6, lane = threadIdx.x & 63;
  int j = blockIdx.x * 4 + w;
  float4 v = ((const float4*)xin)[(size_t)j * 64 + lane];
  float s = v.x + v.y + v.z + v.w;
  for (int m = 1; m < 64; m <<= 1) s += __shfl_xor(s, m);
  float mean = s * (1.0f / 256.0f);
  float dx = v.x - mean, dy = v.y - mean, dz = v.z - mean, dw = v.w - mean;
  float q = dx*dx + dy*dy + dz*dz + dw*dw;
  for (int m = 1; m < 64; m <<= 1) q += __shfl_xor(q, m);
  float rs = rsqrtf(q * (1.0f / 256.0f) + 1e-5f);
  int c0 = lane * 4;
  u16 h0 = f2bf(dx * rs * g[c0+0] + b[c0+0]);
  u16 h1 = f2bf(dy * rs * g[c0+1] + b[c0+1]);
  u16 h2 = f2bf(dz * rs * g[c0+2] + b[c0+2]);
  u16 h3 = f2bf(dw * rs * g[c0+3] + b[c0+3]);
  uint2 pk; pk.x = (u32)h0 | ((u32)h1 << 16); pk.y = (u32)h2 | ((u32)h3 << 16);
  *(uint2*)&out[(size_t)j * 256 + c0] = pk;
}

// ---------- final LN (f32 out) ----------
__global__ void __launch_bounds__(256) ln_final_kernel(const float* __restrict__ xin,
    const float* __restrict__ g, const float* __restrict__ b, float* __restrict__ out){
  int w = threadIdx.x >> 6, lane = threadIdx.x & 63;
  int j = blockIdx.x * 4 + w;
  float4 v = ((const float4*)xin)[(size_t)j * 64 + lane];
  float s = v.x + v.y + v.z + v.w;
  for (int m = 1; m < 64; m <<= 1) s += __shfl_xor(s, m);
  float mean = s * (1.0f / 256.0f);
  float dx = v.x - mean, dy = v.y - mean, dz = v.z - mean, dw = v.w - mean;
  float q = dx*dx + dy*dy + dz*dz + dw*dw;
  for (int m = 1; m < 64; m <<= 1) q += __shfl_xor(q, m);
  float rs = rsqrtf(q * (1.0f / 256.0f) + 1e-5f);
  int c0 = lane * 4;
  float4 o;
  o.x = dx * rs * g[c0+0] + b[c0+0];
  o.y = dy * rs * g[c0+1] + b[c0+1];
  o.z = dz * rs * g[c0+2] + b[c0+2];
  o.w = dw * rs * g[c0+3] + b[c0+3];
  ((float4*)out)[(size_t)j * 64 + lane] = o;
}

// ---------- GEMM2: 256xBN tile, 1024 threads, XCD-chunk swizzle ----------
// EPI 0 (qkv): bf16 out, Q cols (<256) pre-scaled by SC2. EPI 1: gelu->bf16.
// EPI 3 (fc2): f32 out[scatter(row)] = res[row] + v (output stride 256).
// bf16 epilogue: ni INNERMOST so each row's 4x32B col-segments issue
// back-to-back -> L2 write-combines into full 64B lines (fixes 1.45x WRITE amp).
template<int EPI, int BN>
__global__ void __launch_bounds__(1024) gemm2_kernel(
    const u16* __restrict__ A, const u16* __restrict__ Wt,
    const float* __restrict__ bias, int K, int Nn,
    u16* __restrict__ outb, float* __restrict__ outf,
    const float* __restrict__ res, const u64* __restrict__ keys, int shift){
  constexpr int WN = (BN == 256) ? 4 : 2;
  constexpr int WM = 16 / WN;             // 4 or 8
  constexpr int MI = (256 / WM) / 16;     // 4 or 2
  constexpr int NI = (BN / WN) / 16;      // 4
  constexpr int SPANM = 256 / WM;         // 64 or 32
  constexpr int SPANN = BN / WN;          // 64
  __shared__ __align__(16) u16 As[2][256 * 32];
  __shared__ __align__(16) u16 Bs[2][BN * 32];
  int swz = xcd_swz(blockIdx.x, gridDim.x);
  int ntiles = Nn / BN;
  int m0 = (swz / ntiles) * 256;
  int n0 = (swz % ntiles) * BN;
  int tid = threadIdx.x;
  int lane = tid & 63, lc = lane & 15, g = lane >> 4;
  int w = tid >> 6;
  int wm = (BN == 256) ? (w >> 2) : (w >> 1);
  int wn = (BN == 256) ? (w & 3) : (w & 1);
  f32x4 acc[MI][NI];
  #pragma unroll
  for (int mi = 0; mi < MI; ++mi)
    #pragma unroll
    for (int ni = 0; ni < NI; ++ni) acc[mi][ni] = (f32x4){0.f,0.f,0.f,0.f};
  int rA = tid >> 2, sA = tid & 3;
  const u16* Ag = A + (size_t)(m0 + rA) * K + (sA ^ ((rA >> 1) & 3)) * 8;
  int cb = (BN == 256) ? tid : (tid & 511);   // BN=128: both halves stage same chunk
  int rB = cb >> 2, sB = cb & 3;
  const u16* Bg = Wt + (size_t)(n0 + rB) * K + (sB ^ ((rB >> 1) & 3)) * 8;
  int aofs = (tid & ~63) * 8;
  int bofs = (cb & ~63) * 8;
  int nt = K >> 5;
  auto issue = [&](int t, int b){
    int kk = t << 5;
    gload_lds16(Ag + kk, As[b] + aofs);
    gload_lds16(Bg + kk, Bs[b] + bofs);
  };
  issue(0, 0);
  int cur = 0;
  int fsw = (lc >> 1) & 3;                // read swizzle: (row>>1)&3 == (lc>>1)&3
  for (int t = 0; t < nt; ++t){
    if (t + 1 < nt){
      issue(t + 1, cur ^ 1);
      asm volatile("s_waitcnt vmcnt(2)" ::: "memory");   // tile t landed; t+1 in flight
    } else {
      asm volatile("s_waitcnt vmcnt(0)" ::: "memory");
    }
    __builtin_amdgcn_s_barrier();          // publish tile t
    bf16x8 af[MI], bfr[NI];
    #pragma unroll
    for (int mi = 0; mi < MI; ++mi)
      af[mi] = *(const bf16x8*)&As[cur][(wm*SPANM + mi*16 + lc)*32 + (g ^ fsw)*8];
    #pragma unroll
    for (int ni = 0; ni < NI; ++ni)
      bfr[ni] = *(const bf16x8*)&Bs[cur][(wn*SPANN + ni*16 + lc)*32 + (g ^ fsw)*8];
    #pragma unroll
    for (int mi = 0; mi < MI; ++mi)
      #pragma unroll
      for (int ni = 0; ni < NI; ++ni)
        acc[mi][ni] = mfma16(af[mi], bfr[ni], acc[mi][ni]);
    asm volatile("" ::: "memory");         // pin ds_reads above the barrier
    __builtin_amdgcn_s_barrier();          // buf[cur] reusable
    cur ^= 1;
  }
  if constexpr (EPI == 0 || EPI == 1){
    float bv[NI];
    #pragma unroll
    for (int ni = 0; ni < NI; ++ni) bv[ni] = bias[n0 + wn*SPANN + ni*16 + lc];
    #pragma unroll
    for (int mi = 0; mi < MI; ++mi){
      #pragma unroll
      for (int r = 0; r < 4; ++r){
        int row = m0 + wm*SPANM + mi*16 + g*4 + r;
        u16* rowp = outb + (size_t)row * Nn + n0 + wn*SPANN + lc;
        #pragma unroll
        for (int ni = 0; ni < NI; ++ni){   // consecutive 32B segments of one row
          int col = n0 + wn*SPANN + ni*16 + lc;
          float v = acc[mi][ni][r] + bv[ni];
          if constexpr (EPI == 0){
            if (col < 256) v *= 0.25500526f;   // Q pre-scale: (1/sqrt(32))*log2(e)
          } else {
            v = gelu_tanh(v);
          }
          rowp[ni*16] = f2bf_hw(v);
        }
      }
    }
  } else {
    #pragma unroll
    for (int ni = 0; ni < NI; ++ni){
      int col = n0 + wn*SPANN + ni*16 + lc;
      float bv = bias[col];
      #pragma unroll
      for (int mi = 0; mi < MI; ++mi){
        #pragma unroll
        for (int r = 0; r < 4; ++r){
          int row = m0 + wm*SPANM + mi*16 + g*4 + r;
          float v = acc[mi][ni][r] + bv;
          u32 dst = rp_idx(keys, row, shift);
          outf[(size_t)dst * 256 + col] = res[(size_t)row * 256 + col] + v;
        }
      }
    }
  }
}

// ---------- GEMM (128x128, 256 thr): proj (EPI2: res[gather(row)] + v), XCD swizzle ----------
template<int EPI>
__global__ void __launch_bounds__(256) gemm_kernel(
    const u16* __restrict__ A, const u16* __restrict__ Wt,
    const float* __restrict__ bias, int K, int Nn,
    u16* __restrict__ outb, float* __restrict__ outf,
    const float* __restrict__ res, const u64* __restrict__ keys, int shift){
  __shared__ __align__(16) u16 As[2][128 * 32];
  __shared__ __align__(16) u16 Bs[2][128 * 32];
  int swz = xcd_swz(blockIdx.x, gridDim.x);
  int ntiles = Nn / 128;
  int m0 = (swz / ntiles) * 128;
  int n0 = (swz % ntiles) * 128;
  int tid = threadIdx.x;
  int lane = tid & 63, lc = lane & 15, g = lane >> 4;
  int w = tid >> 6, wm = w >> 1, wn = w & 1;
  f32x4 acc[4][4];
  #pragma unroll
  for (int mi = 0; mi < 4; ++mi)
    #pragma unroll
    for (int ni = 0; ni < 4; ++ni) acc[mi][ni] = (f32x4){0.f,0.f,0.f,0.f};
  int r1 = tid >> 2, s1 = tid & 3;
  int r2 = r1 + 64;
  int sw = s1 ^ ((r1 >> 1) & 3);
  const u16* Ag1 = A  + (size_t)(m0 + r1) * K + sw*8;
  const u16* Ag2 = A  + (size_t)(m0 + r2) * K + sw*8;
  const u16* Bg1 = Wt + (size_t)(n0 + r1) * K + sw*8;
  const u16* Bg2 = Wt + (size_t)(n0 + r2) * K + sw*8;
  int wofs = (tid & ~63) * 8;
  int nt = K >> 5;
  gload_lds16(Ag1, As[0] + wofs);
  gload_lds16(Ag2, As[0] + wofs + 2048);
  gload_lds16(Bg1, Bs[0] + wofs);
  gload_lds16(Bg2, Bs[0] + wofs + 2048);
  int cur = 0;
  int fsw = (lc >> 1) & 3;
  for (int t = 0; t < nt; ++t){
    if (t + 1 < nt){
      int kk = (t + 1) << 5;
      gload_lds16(Ag1 + kk, As[cur^1] + wofs);
      gload_lds16(Ag2 + kk, As[cur^1] + wofs + 2048);
      gload_lds16(Bg1 + kk, Bs[cur^1] + wofs);
      gload_lds16(Bg2 + kk, Bs[cur^1] + wofs + 2048);
      asm volatile("s_waitcnt vmcnt(4)" ::: "memory");
    } else {
      asm volatile("s_waitcnt vmcnt(0)" ::: "memory");
    }
    __builtin_amdgcn_s_barrier();
    bf16x8 af[4], bfr[4];
    #pragma unroll
    for (int mi = 0; mi < 4; ++mi)
      af[mi] = *(const bf16x8*)&As[cur][(wm*64 + mi*16 + lc)*32 + (g ^ fsw)*8];
    #pragma unroll
    for (int ni = 0; ni < 4; ++ni)
      bfr[ni] = *(const bf16x8*)&Bs[cur][(wn*64 + ni*16 + lc)*32 + (g ^ fsw)*8];
    #pragma unroll
    for (int mi = 0; mi < 4; ++mi)
      #pragma unroll
      for (int ni = 0; ni < 4; ++ni)
        acc[mi][ni] = mfma16(af[mi], bfr[ni], acc[mi][ni]);
    asm volatile("" ::: "memory");
    __builtin_amdgcn_s_barrier();
    cur ^= 1;
  }
  #pragma unroll
  for (int ni = 0; ni < 4; ++ni){
    int col = n0 + wn*64 + ni*16 + lc;
    float bv = bias[col];
    #pragma unroll
    for (int mi = 0; mi < 4; ++mi){
      #pragma unroll
      for (int r = 0; r < 4; ++r){
        int row = m0 + wm*64 + mi*16 + g*4 + r;
        float v = acc[mi][ni][r] + bv;
        if constexpr (EPI == 2){
          u32 src = rp_idx(keys, row, shift);
          outf[(size_t)row * 256 + col] = res[(size_t)src * 256 + col] + v;
        } else {
          outb[(size_t)row * Nn + col] = f2bf_hw(v);
        }
      }
    }
  }
}

// ---------- attention: swapped-QK, 2 q-tiles per K/V pass ----------
// mfma(K,Q) puts P[q=lc][keys g*4+r] in registers in exact A-frag order.
// Each grp's K/V/w LDS reads feed 12 MFMAs (2 q-tiles); l via unmasked
// w-MFMA (identical columns -> result in every lane, no shfl/cndmask).
#define VSTR 516
#define ATTN_LDS (512*32*2 + 32*VSTR*2 + 512*2)
__global__ void __launch_bounds__(512) attn_kernel(
    const u16* __restrict__ qkvb, const float* __restrict__ dproj,
    u16* __restrict__ o){
  extern __shared__ char smem[];
  u16* Kl = (u16*)smem;                              // [512][32] swizzled chunks
  u16* Vt = (u16*)(smem + 512*32*2);                 // [32 d][VSTR] phys-slot order, w-scaled
  u16* wl = (u16*)(smem + 512*32*2 + 32*VSTR*2);     // [512] w bf16, phys-slot order
  int h = blockIdx.x & 7;
  int base = (blockIdx.x >> 3) * 512;
  int tid = threadIdx.x, w = tid >> 6, lane = tid & 63, lc = lane & 15, g = lane >> 4;
  const float L2E = 1.4426950408889634f;
  for (int i = tid; i < 2048; i += 512){
    int j = i >> 2, s = i & 3;
    int swc = s ^ ((j >> 1) & 3);
    *(uint4*)&Kl[j*32 + s*8] =
      *(const uint4*)&qkvb[(size_t)(base + j)*768 + 256 + h*32 + swc*8];
  }
  for (int i = tid; i < 1024; i += 512){
    int p = i >> 2, d0 = (i & 3) * 8;
    int j0 = 2*p, j1 = j0 + 1;
    float wv0 = fexp2(-L2E * dproj[(size_t)(base + j0)*8 + h]);
    float wv1 = fexp2(-L2E * dproj[(size_t)(base + j1)*8 + h]);
    uint4 r0 = *(const uint4*)&qkvb[(size_t)(base + j0)*768 + 512 + h*32 + d0];
    uint4 r1 = *(const uint4*)&qkvb[(size_t)(base + j1)*768 + 512 + h*32 + d0];
    const u16* p0 = (const u16*)&r0; const u16* p1 = (const u16*)&r1;
    int j5 = j0 & 31, b = j5 >> 4, m = j5 & 15;
    int slot = (j0 & ~31) + 8*(m >> 2) + 4*b + (m & 3);   // even; slot(j1)=slot+1
    #pragma unroll
    for (int e = 0; e < 8; ++e){
      float f0 = __uint_as_float(((u32)p0[e]) << 16) * wv0;
      float f1 = __uint_as_float(((u32)p1[e]) << 16) * wv1;
      u32 pk;
      asm("v_cvt_pk_bf16_f32 %0, %1, %2" : "=v"(pk) : "v"(f0), "v"(f1));
      *(u32*)&Vt[(d0 + e)*VSTR + slot] = pk;
    }
    if (d0 == 0){
      u32 pkw;
      asm("v_cvt_pk_bf16_f32 %0, %1, %2" : "=v"(pkw) : "v"(wv0), "v"(wv1));
      *(u32*)&wl[slot] = pkw;
    }
  }
  __syncthreads();
  const f32x4 zf = {0.f,0.f,0.f,0.f};
  const u16* Qg = qkvb + (size_t)base*768 + h*32;
  int fswk = (lc >> 1) & 3;
  for (int t = 0; t < 2; ++t){
    int q0 = w*64 + t*32;
    bf16x8 qfa = *(const bf16x8*)&Qg[(size_t)(q0 + lc)*768 + g*8];
    bf16x8 qfb = *(const bf16x8*)&Qg[(size_t)(q0 + 16 + lc)*768 + g*8];
    f32x4 oa0 = zf, oa1 = zf, la = zf;
    f32x4 ob0 = zf, ob1 = zf, lb = zf;
    #pragma unroll 4
    for (int grp = 0; grp < 16; ++grp){
      int kb = grp * 32;
      bf16x8 kf0 = *(const bf16x8*)&Kl[(kb + lc)*32 + (g ^ fswk)*8];
      bf16x8 kf1 = *(const bf16x8*)&Kl[(kb + 16 + lc)*32 + (g ^ fswk)*8];
      f32x4 sa0 = mfma16(kf0, qfa, zf);
      f32x4 sa1 = mfma16(kf1, qfa, zf);
      f32x4 sb0 = mfma16(kf0, qfb, zf);
      f32x4 sb1 = mfma16(kf1, qfb, zf);
      #pragma unroll
      for (int r = 0; r < 4; ++r){
        sa0[r] = fexp2(sa0[r]); sa1[r] = fexp2(sa1[r]);
        sb0[r] = fexp2(sb0[r]); sb1[r] = fexp2(sb1[r]);
      }
      u32 ka0, ka1, ka2, ka3, kb0, kb1, kb2, kb3;
      asm("v_cvt_pk_bf16_f32 %0, %1, %2" : "=v"(ka0) : "v"(sa0[0]), "v"(sa0[1]));
      asm("v_cvt_pk_bf16_f32 %0, %1, %2" : "=v"(ka1) : "v"(sa0[2]), "v"(sa0[3]));
      asm("v_cvt_pk_bf16_f32 %0, %1, %2" : "=v"(ka2) : "v"(sa1[0]), "v"(sa1[1]));
      asm("v_cvt_pk_bf16_f32 %0, %1, %2" : "=v"(ka3) : "v"(sa1[2]), "v"(sa1[3]));
      asm("v_cvt_pk_bf16_f32 %0, %1, %2" : "=v"(kb0) : "v"(sb0[0]), "v"(sb0[1]));
      asm("v_cvt_pk_bf16_f32 %0, %1, %2" : "=v"(kb1) : "v"(sb0[2]), "v"(sb0[3]));
      asm("v_cvt_pk_bf16_f32 %0, %1, %2" : "=v"(kb2) : "v"(sb1[0]), "v"(sb1[1]));
      asm("v_cvt_pk_bf16_f32 %0, %1, %2" : "=v"(kb3) : "v"(sb1[2]), "v"(sb1[3]));
      bf16x8 pfa, pfb;
      ((u32*)&pfa)[0] = ka0; ((u32*)&pfa)[1] = ka1;
      ((u32*)&pfa)[2] = ka2; ((u32*)&pfa)[3] = ka3;
      ((u32*)&pfb)[0] = kb0; ((u32*)&pfb)[1] = kb1;
      ((u32*)&pfb)[2] = kb2; ((u32*)&pfb)[3] = kb3;
      bf16x8 v0, v1;
      *(uint2*)&v0       = *(const uint2*)&Vt[lc*VSTR + kb + g*8];
      *((uint2*)&v0 + 1) = *(const uint2*)&Vt[lc*VSTR + kb + g*8 + 4];
      *(uint2*)&v1       = *(const uint2*)&Vt[(16+lc)*VSTR + kb + g*8];
      *((uint2*)&v1 + 1) = *(const uint2*)&Vt[(16+lc)*VSTR + kb + g*8 + 4];
      bf16x8 wf = *(const bf16x8*)&wl[kb + g*8];
      __builtin_amdgcn_s_setprio(1);
      oa0 = mfma16(pfa, v0, oa0);
      oa1 = mfma16(pfa, v1, oa1);
      la  = mfma16(pfa, wf, la);
      ob0 = mfma16(pfb, v0, ob0);
      ob1 = mfma16(pfb, v1, ob1);
      lb  = mfma16(pfb, wf, lb);
      __builtin_amdgcn_s_setprio(0);
    }
    #pragma unroll
    for (int r = 0; r < 4; ++r){
      float inva = frcp(la[r]);
      float invb = frcp(lb[r]);
      size_t tokA = (size_t)(base + q0 + g*4 + r);
      size_t tokB = tokA + 16;
      o[tokA*256 + h*32 + lc]      = f2bf(oa0[r] * inva);
      o[tokA*256 + h*32 + 16 + lc] = f2bf(oa1[r] * inva);
      o[tokB*256 + h*32 + lc]      = f2bf(ob0[r] * invb);
      o[tokB*256 + h*32 + 16 + lc] = f2bf(ob1[r] * invb);
    }
  }
}

// ---------- host ----------
extern "C" void kernel_launch(void* const* d_in, const int* in_sizes, int n_in,
                              void* d_out, int out_size, void* d_ws, size_t ws_size,
                              hipStream_t stream){
  const float* x      = (const float*)d_in[0];
  const float* coords = (const float*)d_in[1];
  const float* ln1_g  = (const float*)d_in[2];
  const float* ln1_b  = (const float*)d_in[3];
  const float* w_qkv  = (const float*)d_in[4];
  const float* b_qkv  = (const float*)d_in[5];
  const float* w_proj = (const float*)d_in[6];
  const float* b_proj = (const float*)d_in[7];
  const float* w_pos  = (const float*)d_in[8];
  // d_in[9] = b_pos: cancels in softmax (row-constant), unused
  const float* ln2_g  = (const float*)d_in[10];
  const float* ln2_b  = (const float*)d_in[11];
  const float* w_fc1  = (const float*)d_in[12];
  const float* b_fc1  = (const float*)d_in[13];
  const float* w_fc2  = (const float*)d_in[14];
  const float* b_fc2  = (const float*)d_in[15];
  const float* norm_g = (const float*)d_in[16];
  const float* norm_b = (const float*)d_in[17];
  float* outp = (float*)d_out;

  // allow >64KB dynamic LDS for attn (idempotent; not a stream op)
  hipFuncSetAttribute((const void*)attn_kernel,
                      hipFuncAttributeMaxDynamicSharedMemorySize, ATTN_LDS);

  char* ws = (char*)d_ws;
  size_t off = 0;
  auto alloc = [&](size_t bytes) -> void* {
    void* p = ws + off;
    off += (bytes + 255) & ~(size_t)255;
    return p;
  };
  u64*   keys   = (u64*)  alloc((size_t)2 * N_TOK * 8);     // both layers
  float* cmm    = (float*)alloc(256);
  float* dproj  = (float*)alloc((size_t)N_TOK * 8 * 4);
  u16*   h      = (u16*)  alloc((size_t)N_TOK * 256 * 2);   // also reused as h2
  u16*   qkvb   = (u16*)  alloc((size_t)N_TOK * 768 * 2);   // also reused as layer-2 output (f32)
  float* x2     = (float*)alloc((size_t)N_TOK * 256 * 4);
  u16*   t      = (u16*)  alloc((size_t)N_TOK * 1024 * 2);  // front 1/4 also reused as attn out o
  float* xA     = (float*)alloc((size_t)N_TOK * 256 * 4);
  u16*   wtqkv  = (u16*)  alloc((size_t)2 * 256 * 768 * 2);
  u16*   wtproj = (u16*)  alloc((size_t)2 * 256 * 256 * 2);
  u16*   wtfc1  = (u16*)  alloc((size_t)2 * 256 * 1024 * 2);
  u16*   wtfc2  = (u16*)  alloc((size_t)2 * 1024 * 256 * 2);
  u16*   o      = t;            // alias: o dead before fc1 writes t
  float* xB     = (float*)qkvb; // alias: layer-2 qkv dead before fc2 writes xB
  (void)in_sizes; (void)n_in; (void)out_size; (void)ws_size;

  minmax_init<<<1, 64, 0, stream>>>((u32*)cmm);
  minmax_atomic<<<384, 256, 0, stream>>>(coords, (u32*)cmm);
  wprep_all<<<1536, 256, 0, stream>>>(w_qkv, w_proj, w_fc1, w_fc2,
                                      wtqkv, wtproj, wtfc1, wtfc2);

  // both layers' sorts, batched: wave-1024 sort, then strided+tail per bitonic level
  codes_kernel<<<256, 256, 0, stream>>>(coords, cmm, keys);
  sort_wave1024<<<64, 64, 0, stream>>>(keys);
  sort_strided<1><<<128, 256, 0, stream>>>(keys, 10, 2048);
  sort_tail1024<<<64, 64, 0, stream>>>(keys, 2048);
  sort_strided<2><<<64, 256, 0, stream>>>(keys, 10, 4096);
  sort_tail1024<<<64, 64, 0, stream>>>(keys, 4096);
  sort_strided<3><<<32, 256, 0, stream>>>(keys, 10, 8192);
  sort_tail1024<<<64, 64, 0, stream>>>(keys, 8192);
  sort_strided<3><<<32, 256, 0, stream>>>(keys, 11, 16384);
  sort_strided<1><<<128, 256, 0, stream>>>(keys, 10, 16384);
  sort_tail1024<<<64, 64, 0, stream>>>(keys, 16384);
  sort_strided<3><<<32, 256, 0, stream>>>(keys, 12, 32768);
  sort_strided<2><<<64, 256, 0, stream>>>(keys, 10, 32768);
  sort_tail1024<<<64, 64, 0, stream>>>(keys, 32768);

  for (int layer = 0; layer < 2; ++layer){
    int shift = (layer & 1) ? 256 : 0;
    const float* xin = (layer == 0) ? x : xA;
    float* xout = (layer == 0) ? xA : xB;
    u64* keyL = keys + (size_t)layer * N_TOK;

    gather_ln1_kernel<<<8192, 256, 0, stream>>>(xin, coords, keyL, shift,
        ln1_g + layer*256, ln1_b + layer*256, w_pos + layer*24, dproj, h);
    gemm2_kernel<0,256><<<384, 1024, 0, stream>>>(h, wtqkv + (size_t)layer*768*256,
        b_qkv + layer*768, 256, 768, qkvb, nullptr, nullptr, nullptr, 0);
    attn_kernel<<<512, 512, ATTN_LDS, stream>>>(qkvb, dproj, o);
    gemm_kernel<2><<<512, 256, 0, stream>>>(o, wtproj + (size_t)layer*256*256,
        b_proj + layer*256, 256, 256, nullptr, x2, xin, keyL, shift);
    ln_bf16_kernel<<<8192, 256, 0, stream>>>(x2, ln2_g + layer*256, ln2_b + layer*256, h);
    gemm2_kernel<1,256><<<512, 1024, 0, stream>>>(h, wtfc1 + (size_t)layer*1024*256,
        b_fc1 + layer*1024, 256, 1024, t, nullptr, nullptr, nullptr, 0);
    gemm2_kernel<3,128><<<256, 1024, 0, stream>>>(t, wtfc2 + (size_t)layer*256*1024,
        b_fc2 + layer*256, 1024, 256, nullptr, xout, x2, keyL, shift);
  }
  ln_final_kernel<<<8192, 256, 0, stream>>>(xB, norm_g, norm_b, outp);
}